// Round 8
// baseline (173.152 us; speedup 1.0000x reference)
//
#include <hip/hip_runtime.h>
#include <float.h>
#include <math.h>
#include <stdint.h>

// VQ-VAE VectorQuantizer — round 10: 2-deep cb prefetch + device finalize.
//
// z_e: (32, 256, 32, 32) fp32, weight: (1024, 256) fp32
// outputs concat: quantized_st (8388608) + loss (1) + perplexity (1)
//
// r9 confirmed the mt-sweep load->MFMA latency serialization theory:
// 1-deep ping-pong prefetch cut main 51.7 -> 44.0 us. But one MFMA block
// (~160 cy) < loaded-L2 latency (~250-400 cy), so part stays exposed.
// r10: (1) 2-deep prefetch — 3 rotating register buffers, vmcnt wait for
// tile mt sits behind TWO MFMA+compare blocks; (2) first two cb tiles
// issued before phase A so phase-A z-load latency covers them; (3) vq_final
// folded into main via r6's proven done-counter (saves a dispatch gap).
// Timed-window budget (r8/r9 counters): 43 us harness re-poison fill (at
// HBM roofline, fixed) + main + ~20 us gaps + prep.
//
// score[k][n] = wsq[k] - 2*w_k.z_n  via  mfma_f32_16x16x32_bf16:
//   A (M=16 codes)  = -2*w  (bf16, A-frag order, streamed from L2)
//   B (N=16 z vecs) =  z    (bf16, register-resident, 4 N-tiles = 64 z/wave)
//   C init          =  wsq[k]
//
// ws layout (bytes): [0,4096) wsq f32 | [4096,8192) counts u32
//                    [8192,8196) loss_sum f32 | [8196,8200) done u32
//                    [16384, 16384+524288) cbfrag bf16

#define NB   32
#define NC   256
#define NHW  1024
#define NK   1024
#define NELEM (NB*NC*NHW)   // 8388608

typedef __attribute__((ext_vector_type(8))) short bf16x8;   // 8 bf16 = 4 VGPRs
typedef __attribute__((ext_vector_type(4))) float f32x4;

__device__ __forceinline__ unsigned short f2bf(float f) {   // RTN fp32->bf16
    unsigned u = __float_as_uint(f);
    u += 0x7FFFu + ((u >> 16) & 1u);
    return (unsigned short)(u >> 16);
}

// ---------------- K1: prep — pack A-frags (-2w bf16) + wsq + zero accums ---
__global__ __launch_bounds__(256) void vq_prep(const float* __restrict__ w,
                                               unsigned short* __restrict__ cb,
                                               float* __restrict__ wsq,
                                               unsigned int* __restrict__ counts,
                                               float* __restrict__ loss_sum,
                                               unsigned int* __restrict__ done) {
    __shared__ float swsq[4][16];
    const int t   = blockIdx.x;          // code tile 0..63 (16 codes each)
    const int tid = threadIdx.x;
    float sq = 0.f;
#pragma unroll
    for (int rep = 0; rep < 2; ++rep) {
        const int p = tid + rep * 256;   // 0..511
        const int cc = p >> 6, l = p & 63;
        const int n = l & 15, quad = l >> 4;
        const float* src = w + (t * 16 + n) * NC + cc * 32 + quad * 8;
        const float4 f0 = *(const float4*)src;
        const float4 f1 = *(const float4*)(src + 4);
        union { unsigned short u[8]; uint4 v; } pk;
        pk.u[0] = f2bf(-2.f * f0.x); pk.u[1] = f2bf(-2.f * f0.y);
        pk.u[2] = f2bf(-2.f * f0.z); pk.u[3] = f2bf(-2.f * f0.w);
        pk.u[4] = f2bf(-2.f * f1.x); pk.u[5] = f2bf(-2.f * f1.y);
        pk.u[6] = f2bf(-2.f * f1.z); pk.u[7] = f2bf(-2.f * f1.w);
        *(uint4*)(cb + (size_t)t * 4096 + cc * 512 + l * 8) = pk.v;
        sq = fmaf(f0.x, f0.x, sq); sq = fmaf(f0.y, f0.y, sq);
        sq = fmaf(f0.z, f0.z, sq); sq = fmaf(f0.w, f0.w, sq);
        sq = fmaf(f1.x, f1.x, sq); sq = fmaf(f1.y, f1.y, sq);
        sq = fmaf(f1.z, f1.z, sq); sq = fmaf(f1.w, f1.w, sq);
    }
    sq += __shfl_xor(sq, 16, 64);
    sq += __shfl_xor(sq, 32, 64);
    const int wv = tid >> 6, lane = tid & 63;
    if (lane < 16) swsq[wv][lane] = sq;
    __syncthreads();
    if (tid < 16)
        wsq[t * 16 + tid] = swsq[0][tid] + swsq[1][tid] + swsq[2][tid] + swsq[3][tid];
    if (t == 0) {
        for (int i = tid; i < NK; i += 256) counts[i] = 0u;
        if (tid == 0) { loss_sum[0] = 0.f; done[0] = 0u; }
    }
}

// ---------------- K2: main — MFMA argmin (2-deep prefetch) + gather + loss -
// grid 512 x 256 (4 waves). Block: 64 z vecs (b = bid>>4, hw0 = (bid&15)*64).
// Wave wv owns code quarter [wv*256, wv*256+256).
__global__ __launch_bounds__(256, 2) void vq_main8(const float* __restrict__ z,
                                                   const float* __restrict__ w,
                                                   const float* __restrict__ wsq,
                                                   const unsigned short* __restrict__ cb,
                                                   unsigned int* __restrict__ counts,
                                                   float* __restrict__ loss_sum,
                                                   unsigned int* __restrict__ done,
                                                   float* __restrict__ out) {
    __shared__ float sval[4][64];
    __shared__ int   sidx[4][64];
    __shared__ int   fidx[64];
    __shared__ float lred[4];
    __shared__ int   amlast;

    const int tid  = threadIdx.x;
    const int wv   = tid >> 6;            // code quarter 0..3
    const int lane = tid & 63;
    const int n    = lane & 15;
    const int quad = lane >> 4;
    const int bid  = blockIdx.x;
    const int b    = bid >> 4;            // batch image
    const int hw0  = (bid & 15) << 6;     // block's 64-row hw origin

    const float* zb = z + (size_t)b * (NC * NHW);
    const unsigned short* ap0 = cb + (size_t)(wv * 16) * 4096 + lane * 8;

    // ---- issue first two cb tiles NOW: phase-A z latency covers them ------
    bf16x8 pf[3][8];                      // 3 rotating prefetch buffers
#pragma unroll
    for (int cc = 0; cc < 8; ++cc) pf[0][cc] = *(const bf16x8*)(ap0 + cc * 512);
#pragma unroll
    for (int cc = 0; cc < 8; ++cc) pf[1][cc] = *(const bf16x8*)(ap0 + 4096 + cc * 512);

    // ---- Phase A: 64 z vectors -> register B-fragments (bf16) -------------
    bf16x8 bfr[4][8];
#pragma unroll
    for (int nt = 0; nt < 4; ++nt) {
#pragma unroll
        for (int cc = 0; cc < 8; ++cc) {
            const float* zp = zb + (size_t)(cc * 32 + quad * 8) * NHW + hw0 + nt * 16 + n;
            union { unsigned short u[8]; bf16x8 v; } pk;
#pragma unroll
            for (int j = 0; j < 8; ++j) pk.u[j] = f2bf(zp[(size_t)j * NHW]);
            bfr[nt][cc] = pk.v;
        }
    }

    // ---- Main loop: 2-deep rotating prefetch of cb tiles ------------------
    // Full unroll -> all pf indices compile-time (no scratch; rule #20).
    float bv[4] = {FLT_MAX, FLT_MAX, FLT_MAX, FLT_MAX};
    int   bi[4] = {0, 0, 0, 0};

#pragma unroll 16
    for (int mt = 0; mt < 16; ++mt) {
        if (mt + 2 < 16) {
            const unsigned short* apn = ap0 + (size_t)(mt + 2) * 4096;
#pragma unroll
            for (int cc = 0; cc < 8; ++cc)
                pf[(mt + 2) % 3][cc] = *(const bf16x8*)(apn + cc * 512);
        }
        const int kt = wv * 256 + mt * 16;
        const f32x4 w4 = *(const f32x4*)(wsq + kt + quad * 4);
        f32x4 acc[4];
#pragma unroll
        for (int nt = 0; nt < 4; ++nt) acc[nt] = w4;
#pragma unroll
        for (int cc = 0; cc < 8; ++cc) {
            const bf16x8 af = pf[mt % 3][cc];
            acc[0] = __builtin_amdgcn_mfma_f32_16x16x32_bf16(af, bfr[0][cc], acc[0], 0, 0, 0);
            acc[1] = __builtin_amdgcn_mfma_f32_16x16x32_bf16(af, bfr[1][cc], acc[1], 0, 0, 0);
            acc[2] = __builtin_amdgcn_mfma_f32_16x16x32_bf16(af, bfr[2][cc], acc[2], 0, 0, 0);
            acc[3] = __builtin_amdgcn_mfma_f32_16x16x32_bf16(af, bfr[3][cc], acc[3], 0, 0, 0);
        }
#pragma unroll
        for (int nt = 0; nt < 4; ++nt) {
#pragma unroll
            for (int r = 0; r < 4; ++r) {
                const float v = acc[nt][r];
                if (v < bv[nt]) { bv[nt] = v; bi[nt] = kt + quad * 4 + r; }
            }
        }
    }

    // ---- cross-quad argmin (lanes n, n+16, n+32, n+48) --------------------
#pragma unroll
    for (int nt = 0; nt < 4; ++nt) {
#pragma unroll
        for (int off = 16; off <= 32; off <<= 1) {
            const float ov = __shfl_xor(bv[nt], off, 64);
            const int   ok = __shfl_xor(bi[nt], off, 64);
            if (ov < bv[nt] || (ov == bv[nt] && ok < bi[nt])) { bv[nt] = ov; bi[nt] = ok; }
        }
    }
    if (lane < 16) {
#pragma unroll
        for (int nt = 0; nt < 4; ++nt) {
            sval[wv][nt * 16 + lane] = bv[nt];
            sidx[wv][nt * 16 + lane] = bi[nt];
        }
    }
    __syncthreads();

    // ---- cross-wave argmin over the 4 code quarters -----------------------
    if (tid < 64) {
        float bestv = sval[0][tid];
        int   besti = sidx[0][tid];
#pragma unroll
        for (int q = 1; q < 4; ++q) {
            const float v = sval[q][tid];
            const int   k = sidx[q][tid];
            if (v < bestv || (v == bestv && k < besti)) { bestv = v; besti = k; }
        }
        fidx[tid] = besti;
        atomicAdd(&counts[besti], 1u);
    }
    __syncthreads();

    // ---- Phase 2: gather codebook rows, write quantized, accumulate loss --
    float lsum = 0.f;
    const int hwl = tid & 63;
    const int cg  = tid >> 6;             // 0..3 -> c range [cg*64, cg*64+64)
    const int myk = fidx[hwl];
    const float* wr  = w + myk * NC;
    const float* zp2 = zb + hw0 + hwl;
    float*       op  = out + (size_t)b * (NC * NHW) + hw0 + hwl;
#pragma unroll 4
    for (int p = 0; p < 16; ++p) {
        const int c0 = cg * 64 + p * 4;
        const float4 q4 = *(const float4*)(wr + c0);
        const float qa[4] = {q4.x, q4.y, q4.z, q4.w};
#pragma unroll
        for (int u = 0; u < 4; ++u) {
            const int c = c0 + u;
            const float zv = zp2[(size_t)c * NHW];
            const float d = qa[u] - zv;
            lsum = fmaf(d, d, lsum);
            op[(size_t)c * NHW] = qa[u];
        }
    }
#pragma unroll
    for (int off = 32; off; off >>= 1) lsum += __shfl_down(lsum, off, 64);
    if (lane == 0) lred[wv] = lsum;
    __syncthreads();
    if (tid == 0)
        atomicAdd(loss_sum, lred[0] + lred[1] + lred[2] + lred[3]);

    // ---- device-side finalize: last block computes loss + perplexity ------
    if (tid == 0) {
        __threadfence();                               // publish atomics
        amlast = (atomicAdd(done, 1u) == (unsigned)(gridDim.x - 1)) ? 1 : 0;
    }
    __syncthreads();
    if (amlast) {                                      // block-uniform branch
        float s = 0.f;
#pragma unroll
        for (int p = 0; p < 4; ++p) {
            const unsigned cnt = atomicAdd(&counts[tid + p * 256], 0u);  // coherent read
            const float pr = (float)cnt * (1.f / 32768.f);
            s = fmaf(pr, logf(pr + 1e-10f), s);
        }
#pragma unroll
        for (int off = 32; off; off >>= 1) s += __shfl_down(s, off, 64);
        __syncthreads();                               // lred reuse safe
        if (lane == 0) lred[wv] = s;
        __syncthreads();
        if (tid == 0) {
            const float tot = lred[0] + lred[1] + lred[2] + lred[3];
            const float lv  = atomicAdd(loss_sum, 0.f);  // coherent read
            out[NELEM]     = lv * (1.25f / (float)NELEM);
            out[NELEM + 1] = expf(-tot);
        }
    }
}

extern "C" void kernel_launch(void* const* d_in, const int* in_sizes, int n_in,
                              void* d_out, int out_size, void* d_ws, size_t ws_size,
                              hipStream_t stream) {
    const float* z = (const float*)d_in[0];
    const float* w = (const float*)d_in[1];
    float* out = (float*)d_out;

    float*          wsq      = (float*)d_ws;
    unsigned int*   counts   = (unsigned int*)((char*)d_ws + 4096);
    float*          loss_sum = (float*)((char*)d_ws + 8192);
    unsigned int*   done     = (unsigned int*)((char*)d_ws + 8196);
    unsigned short* cbfrag   = (unsigned short*)((char*)d_ws + 16384);  // 512 KB

    vq_prep <<<64,  256, 0, stream>>>(w, cbfrag, wsq, counts, loss_sum, done);
    vq_main8<<<512, 256, 0, stream>>>(z, w, wsq, cbfrag, counts, loss_sum, done, out);
}

// Round 10
// 130.715 us; speedup vs baseline: 1.3246x; 1.3246x over previous
//
#include <hip/hip_runtime.h>
#include <float.h>
#include <math.h>
#include <stdint.h>

// VQ-VAE VectorQuantizer — round 12: r9 (verified best, 115.3 us) + r6's
// proven device-side finalize. No new sync structures.
//
// z_e: (32, 256, 32, 32) fp32, weight: (1024, 256) fp32
// outputs concat: quantized_st (8388608) + loss (1) + perplexity (1)
//
// History: r9's 1-deep register ping-pong on the cb stream cut main
// 51.7 -> 44.0 us (load->MFMA latency-cover mechanism confirmed). Depth-2
// attempts both died: registers spill (r10, FETCH/WRITE tripled); barrier-
// free LDS FIFO races (r11, perplexity->1: stale LDS => scores = wsq[k] =>
// one code for all positions). Budget: 43 us harness fill (HBM roofline) +
// 44 main + ~4 prep + ~2 final + ~22 us dispatch gaps. r12 removes one
// boundary: vq_final folds into main via r6's done-counter tail (that tail
// passed correctness in r6). Main loop byte-identical to r9.
//
// score[k][n] = wsq[k] - 2*w_k.z_n  via  mfma_f32_16x16x32_bf16:
//   A (M=16 codes)  = -2*w  (bf16, A-frag order, streamed from L2,
//                            1-deep register ping-pong)
//   B (N=16 z vecs) =  z    (bf16, register-resident, 4 N-tiles = 64 z/wave)
//   C init          =  wsq[k]
//
// ws layout (bytes): [0,4096) wsq f32 | [4096,8192) counts u32
//                    [8192,8196) loss_sum f32 | [8196,8200) done u32
//                    [16384, 16384+524288) cbfrag bf16

#define NB   32
#define NC   256
#define NHW  1024
#define NK   1024
#define NELEM (NB*NC*NHW)   // 8388608

typedef __attribute__((ext_vector_type(8))) short bf16x8;   // 8 bf16 = 4 VGPRs
typedef __attribute__((ext_vector_type(4))) float f32x4;

__device__ __forceinline__ unsigned short f2bf(float f) {   // RTN fp32->bf16
    unsigned u = __float_as_uint(f);
    u += 0x7FFFu + ((u >> 16) & 1u);
    return (unsigned short)(u >> 16);
}

// ---------------- K1: prep — pack A-frags (-2w bf16) + wsq + zero accums ---
__global__ __launch_bounds__(256) void vq_prep(const float* __restrict__ w,
                                               unsigned short* __restrict__ cb,
                                               float* __restrict__ wsq,
                                               unsigned int* __restrict__ counts,
                                               float* __restrict__ loss_sum,
                                               unsigned int* __restrict__ done) {
    __shared__ float swsq[4][16];
    const int t   = blockIdx.x;          // code tile 0..63 (16 codes each)
    const int tid = threadIdx.x;
    float sq = 0.f;
#pragma unroll
    for (int rep = 0; rep < 2; ++rep) {
        const int p = tid + rep * 256;   // 0..511
        const int cc = p >> 6, l = p & 63;
        const int n = l & 15, quad = l >> 4;
        const float* src = w + (t * 16 + n) * NC + cc * 32 + quad * 8;
        const float4 f0 = *(const float4*)src;
        const float4 f1 = *(const float4*)(src + 4);
        union { unsigned short u[8]; uint4 v; } pk;
        pk.u[0] = f2bf(-2.f * f0.x); pk.u[1] = f2bf(-2.f * f0.y);
        pk.u[2] = f2bf(-2.f * f0.z); pk.u[3] = f2bf(-2.f * f0.w);
        pk.u[4] = f2bf(-2.f * f1.x); pk.u[5] = f2bf(-2.f * f1.y);
        pk.u[6] = f2bf(-2.f * f1.z); pk.u[7] = f2bf(-2.f * f1.w);
        *(uint4*)(cb + (size_t)t * 4096 + cc * 512 + l * 8) = pk.v;
        sq = fmaf(f0.x, f0.x, sq); sq = fmaf(f0.y, f0.y, sq);
        sq = fmaf(f0.z, f0.z, sq); sq = fmaf(f0.w, f0.w, sq);
        sq = fmaf(f1.x, f1.x, sq); sq = fmaf(f1.y, f1.y, sq);
        sq = fmaf(f1.z, f1.z, sq); sq = fmaf(f1.w, f1.w, sq);
    }
    sq += __shfl_xor(sq, 16, 64);
    sq += __shfl_xor(sq, 32, 64);
    const int wv = tid >> 6, lane = tid & 63;
    if (lane < 16) swsq[wv][lane] = sq;
    __syncthreads();
    if (tid < 16)
        wsq[t * 16 + tid] = swsq[0][tid] + swsq[1][tid] + swsq[2][tid] + swsq[3][tid];
    if (t == 0) {
        for (int i = tid; i < NK; i += 256) counts[i] = 0u;
        if (tid == 0) { loss_sum[0] = 0.f; done[0] = 0u; }
    }
}

// ---------------- K2: main — ping-pong MFMA argmin + gather + loss + final -
// grid 512 x 256 (4 waves). Block: 64 z vecs (b = bid>>4, hw0 = (bid&15)*64).
// Wave wv owns code quarter [wv*256, wv*256+256).
__global__ __launch_bounds__(256, 2) void vq_main10(const float* __restrict__ z,
                                                    const float* __restrict__ w,
                                                    const float* __restrict__ wsq,
                                                    const unsigned short* __restrict__ cb,
                                                    unsigned int* __restrict__ counts,
                                                    float* __restrict__ loss_sum,
                                                    unsigned int* __restrict__ done,
                                                    float* __restrict__ out) {
    __shared__ float sval[4][64];
    __shared__ int   sidx[4][64];
    __shared__ int   fidx[64];
    __shared__ float lred[4];
    __shared__ int   amlast;

    const int tid  = threadIdx.x;
    const int wv   = tid >> 6;            // code quarter 0..3
    const int lane = tid & 63;
    const int n    = lane & 15;
    const int quad = lane >> 4;
    const int bid  = blockIdx.x;
    const int b    = bid >> 4;            // batch image
    const int hw0  = (bid & 15) << 6;     // block's 64-row hw origin

    const float* zb = z + (size_t)b * (NC * NHW);

    // ---- Phase A: 64 z vectors -> register B-fragments (bf16) -------------
    bf16x8 bfr[4][8];
#pragma unroll
    for (int nt = 0; nt < 4; ++nt) {
#pragma unroll
        for (int cc = 0; cc < 8; ++cc) {
            const float* zp = zb + (size_t)(cc * 32 + quad * 8) * NHW + hw0 + nt * 16 + n;
            union { unsigned short u[8]; bf16x8 v; } pk;
#pragma unroll
            for (int j = 0; j < 8; ++j) pk.u[j] = f2bf(zp[(size_t)j * NHW]);
            bfr[nt][cc] = pk.v;
        }
    }

    // ---- Main loop: ping-pong prefetch of cb tiles (r9, verified) ---------
    float bv[4] = {FLT_MAX, FLT_MAX, FLT_MAX, FLT_MAX};
    int   bi[4] = {0, 0, 0, 0};
    const unsigned short* ap0 = cb + (size_t)(wv * 16) * 4096 + lane * 8;

    bf16x8 pa[8], pb[8];
#pragma unroll
    for (int cc = 0; cc < 8; ++cc) pa[cc] = *(const bf16x8*)(ap0 + cc * 512);

#define MT_BODY(MT, CUR, NXT, PREF)                                            \
    {                                                                          \
        if (PREF) {                                                            \
            const unsigned short* apn = ap0 + (size_t)((MT) + 1) * 4096;       \
            _Pragma("unroll")                                                  \
            for (int cc = 0; cc < 8; ++cc)                                     \
                NXT[cc] = *(const bf16x8*)(apn + cc * 512);                    \
        }                                                                      \
        const int kt = wv * 256 + (MT) * 16;                                   \
        const f32x4 w4 = *(const f32x4*)(wsq + kt + quad * 4);                 \
        f32x4 acc[4];                                                          \
        _Pragma("unroll")                                                      \
        for (int nt = 0; nt < 4; ++nt) acc[nt] = w4;                           \
        _Pragma("unroll")                                                      \
        for (int cc = 0; cc < 8; ++cc) {                                       \
            acc[0] = __builtin_amdgcn_mfma_f32_16x16x32_bf16(CUR[cc], bfr[0][cc], acc[0], 0, 0, 0); \
            acc[1] = __builtin_amdgcn_mfma_f32_16x16x32_bf16(CUR[cc], bfr[1][cc], acc[1], 0, 0, 0); \
            acc[2] = __builtin_amdgcn_mfma_f32_16x16x32_bf16(CUR[cc], bfr[2][cc], acc[2], 0, 0, 0); \
            acc[3] = __builtin_amdgcn_mfma_f32_16x16x32_bf16(CUR[cc], bfr[3][cc], acc[3], 0, 0, 0); \
        }                                                                      \
        _Pragma("unroll")                                                      \
        for (int nt = 0; nt < 4; ++nt) {                                       \
            _Pragma("unroll")                                                  \
            for (int r = 0; r < 4; ++r) {                                      \
                const float v = acc[nt][r];                                    \
                if (v < bv[nt]) { bv[nt] = v; bi[nt] = kt + quad * 4 + r; }    \
            }                                                                  \
        }                                                                      \
    }

    for (int mt2 = 0; mt2 < 8; ++mt2) {
        const int mt = mt2 * 2;
        MT_BODY(mt,     pa, pb, true);
        MT_BODY(mt + 1, pb, pa, (mt2 < 7));
    }
#undef MT_BODY

    // ---- cross-quad argmin (lanes n, n+16, n+32, n+48) --------------------
#pragma unroll
    for (int nt = 0; nt < 4; ++nt) {
#pragma unroll
        for (int off = 16; off <= 32; off <<= 1) {
            const float ov = __shfl_xor(bv[nt], off, 64);
            const int   ok = __shfl_xor(bi[nt], off, 64);
            if (ov < bv[nt] || (ov == bv[nt] && ok < bi[nt])) { bv[nt] = ov; bi[nt] = ok; }
        }
    }
    if (lane < 16) {
#pragma unroll
        for (int nt = 0; nt < 4; ++nt) {
            sval[wv][nt * 16 + lane] = bv[nt];
            sidx[wv][nt * 16 + lane] = bi[nt];
        }
    }
    __syncthreads();

    // ---- cross-wave argmin over the 4 code quarters -----------------------
    if (tid < 64) {
        float bestv = sval[0][tid];
        int   besti = sidx[0][tid];
#pragma unroll
        for (int q = 1; q < 4; ++q) {
            const float v = sval[q][tid];
            const int   k = sidx[q][tid];
            if (v < bestv || (v == bestv && k < besti)) { bestv = v; besti = k; }
        }
        fidx[tid] = besti;
        atomicAdd(&counts[besti], 1u);
    }
    __syncthreads();

    // ---- Phase 2: gather codebook rows, write quantized, accumulate loss --
    float lsum = 0.f;
    const int hwl = tid & 63;
    const int cg  = tid >> 6;             // 0..3 -> c range [cg*64, cg*64+64)
    const int myk = fidx[hwl];
    const float* wr  = w + myk * NC;
    const float* zp2 = zb + hw0 + hwl;
    float*       op  = out + (size_t)b * (NC * NHW) + hw0 + hwl;
#pragma unroll 4
    for (int p = 0; p < 16; ++p) {
        const int c0 = cg * 64 + p * 4;
        const float4 q4 = *(const float4*)(wr + c0);
        const float qa[4] = {q4.x, q4.y, q4.z, q4.w};
#pragma unroll
        for (int u = 0; u < 4; ++u) {
            const int c = c0 + u;
            const float zv = zp2[(size_t)c * NHW];
            const float d = qa[u] - zv;
            lsum = fmaf(d, d, lsum);
            op[(size_t)c * NHW] = qa[u];
        }
    }
#pragma unroll
    for (int off = 32; off; off >>= 1) lsum += __shfl_down(lsum, off, 64);
    if (lane == 0) lred[wv] = lsum;
    __syncthreads();
    if (tid == 0)
        atomicAdd(loss_sum, lred[0] + lred[1] + lred[2] + lred[3]);

    // ---- device-side finalize (r6-proven): last block does loss+perplexity
    if (tid == 0) {
        __threadfence();                               // publish atomics
        amlast = (atomicAdd(done, 1u) == (unsigned)(gridDim.x - 1)) ? 1 : 0;
    }
    __syncthreads();
    if (amlast) {                                      // block-uniform branch
        float s = 0.f;
#pragma unroll
        for (int p = 0; p < 4; ++p) {
            const unsigned cnt = atomicAdd(&counts[tid + p * 256], 0u);  // coherent read
            const float pr = (float)cnt * (1.f / 32768.f);
            s = fmaf(pr, logf(pr + 1e-10f), s);
        }
#pragma unroll
        for (int off = 32; off; off >>= 1) s += __shfl_down(s, off, 64);
        __syncthreads();                               // lred reuse safe
        if (lane == 0) lred[wv] = s;
        __syncthreads();
        if (tid == 0) {
            const float tot = lred[0] + lred[1] + lred[2] + lred[3];
            const float lv  = atomicAdd(loss_sum, 0.f);  // coherent read
            out[NELEM]     = lv * (1.25f / (float)NELEM);
            out[NELEM + 1] = expf(-tot);
        }
    }
}

extern "C" void kernel_launch(void* const* d_in, const int* in_sizes, int n_in,
                              void* d_out, int out_size, void* d_ws, size_t ws_size,
                              hipStream_t stream) {
    const float* z = (const float*)d_in[0];
    const float* w = (const float*)d_in[1];
    float* out = (float*)d_out;

    float*          wsq      = (float*)d_ws;
    unsigned int*   counts   = (unsigned int*)((char*)d_ws + 4096);
    float*          loss_sum = (float*)((char*)d_ws + 8192);
    unsigned int*   done     = (unsigned int*)((char*)d_ws + 8196);
    unsigned short* cbfrag   = (unsigned short*)((char*)d_ws + 16384);  // 512 KB

    vq_prep  <<<64,  256, 0, stream>>>(w, cbfrag, wsq, counts, loss_sum, done);
    vq_main10<<<512, 256, 0, stream>>>(z, w, wsq, cbfrag, counts, loss_sum, done, out);
}

// Round 11
// 115.589 us; speedup vs baseline: 1.4980x; 1.1309x over previous
//
#include <hip/hip_runtime.h>
#include <float.h>
#include <math.h>
#include <stdint.h>

// VQ-VAE VectorQuantizer — round 13: r9 (verified best) + de-duplicated
// phase A (per-wave z pack -> LDS -> shared B-frags).
//
// z_e: (32, 256, 32, 32) fp32, weight: (1024, 256) fp32
// outputs concat: quantized_st (8388608) + loss (1) + perplexity (1)
//
// History: r9 ping-pong cb prefetch = verified best (main 44 us, total
// 115.3). r12's fused finalize tail REGRESSED main 44->61.5 (likely the
// 512 per-block device-scope __threadfence L2 writebacks thrashing the cb
// stream) -> reverted to 3 dispatches. r8 ablation: phase A ~ 12 us of main.
// Overlooked: all 4 waves load the SAME 64 z columns — 4x duplicated work.
// r13: each wave packs only ITS N-tile (64 scalar loads + 64 f2bf per lane,
// /4), writes the 8 KB frag block to LDS, one __syncthreads, then all waves
// ds_read_b128 all four N-tiles (lane*16-contiguous 1 KB blocks = 0-conflict,
// proven r0/r9). Frag bytes bit-identical -> same argmin, same outputs.
// pa (first cb tile) now issues BEFORE phase A so L2 latency hides under z.
//
// score[k][n] = wsq[k] - 2*w_k.z_n  via  mfma_f32_16x16x32_bf16:
//   A (M=16 codes)  = -2*w  (bf16, A-frag order, streamed from L2,
//                            1-deep register ping-pong)
//   B (N=16 z vecs) =  z    (bf16, packed once per block via LDS)
//   C init          =  wsq[k]
//
// ws layout (bytes): [0,4096) wsq f32 | [4096,8192) counts u32
//                    [8192,8196) loss_sum f32 | [16384, 16384+524288) cbfrag

#define NB   32
#define NC   256
#define NHW  1024
#define NK   1024
#define NELEM (NB*NC*NHW)   // 8388608

typedef __attribute__((ext_vector_type(8))) short bf16x8;   // 8 bf16 = 4 VGPRs
typedef __attribute__((ext_vector_type(4))) float f32x4;

__device__ __forceinline__ unsigned short f2bf(float f) {   // RTN fp32->bf16
    unsigned u = __float_as_uint(f);
    u += 0x7FFFu + ((u >> 16) & 1u);
    return (unsigned short)(u >> 16);
}

// ---------------- K1: prep — pack A-frags (-2w bf16) + wsq + zero accums ---
__global__ __launch_bounds__(256) void vq_prep(const float* __restrict__ w,
                                               unsigned short* __restrict__ cb,
                                               float* __restrict__ wsq,
                                               unsigned int* __restrict__ counts,
                                               float* __restrict__ loss_sum) {
    __shared__ float swsq[4][16];
    const int t   = blockIdx.x;          // code tile 0..63 (16 codes each)
    const int tid = threadIdx.x;
    float sq = 0.f;
#pragma unroll
    for (int rep = 0; rep < 2; ++rep) {
        const int p = tid + rep * 256;   // 0..511
        const int cc = p >> 6, l = p & 63;
        const int n = l & 15, quad = l >> 4;
        const float* src = w + (t * 16 + n) * NC + cc * 32 + quad * 8;
        const float4 f0 = *(const float4*)src;
        const float4 f1 = *(const float4*)(src + 4);
        union { unsigned short u[8]; uint4 v; } pk;
        pk.u[0] = f2bf(-2.f * f0.x); pk.u[1] = f2bf(-2.f * f0.y);
        pk.u[2] = f2bf(-2.f * f0.z); pk.u[3] = f2bf(-2.f * f0.w);
        pk.u[4] = f2bf(-2.f * f1.x); pk.u[5] = f2bf(-2.f * f1.y);
        pk.u[6] = f2bf(-2.f * f1.z); pk.u[7] = f2bf(-2.f * f1.w);
        *(uint4*)(cb + (size_t)t * 4096 + cc * 512 + l * 8) = pk.v;
        sq = fmaf(f0.x, f0.x, sq); sq = fmaf(f0.y, f0.y, sq);
        sq = fmaf(f0.z, f0.z, sq); sq = fmaf(f0.w, f0.w, sq);
        sq = fmaf(f1.x, f1.x, sq); sq = fmaf(f1.y, f1.y, sq);
        sq = fmaf(f1.z, f1.z, sq); sq = fmaf(f1.w, f1.w, sq);
    }
    sq += __shfl_xor(sq, 16, 64);
    sq += __shfl_xor(sq, 32, 64);
    const int wv = tid >> 6, lane = tid & 63;
    if (lane < 16) swsq[wv][lane] = sq;
    __syncthreads();
    if (tid < 16)
        wsq[t * 16 + tid] = swsq[0][tid] + swsq[1][tid] + swsq[2][tid] + swsq[3][tid];
    if (t == 0) {
        for (int i = tid; i < NK; i += 256) counts[i] = 0u;
        if (tid == 0) loss_sum[0] = 0.f;
    }
}

// ---------------- K2: main — shared z-frags + ping-pong MFMA argmin --------
// grid 512 x 256 (4 waves). Block: 64 z vecs (b = bid>>4, hw0 = (bid&15)*64).
// Wave wv owns code quarter [wv*256, wv*256+256) AND packs z N-tile nt=wv.
__global__ __launch_bounds__(256, 2) void vq_main11(const float* __restrict__ z,
                                                    const float* __restrict__ w,
                                                    const float* __restrict__ wsq,
                                                    const unsigned short* __restrict__ cb,
                                                    unsigned int* __restrict__ counts,
                                                    float* __restrict__ loss_sum,
                                                    float* __restrict__ out) {
    __shared__ __align__(16) unsigned short zfrag[4][8][512];  // 32 KB frag blocks
    __shared__ float sval[4][64];
    __shared__ int   sidx[4][64];
    __shared__ int   fidx[64];
    __shared__ float lred[4];

    const int tid  = threadIdx.x;
    const int wv   = tid >> 6;            // code quarter 0..3 (= packed N-tile)
    const int lane = tid & 63;
    const int n    = lane & 15;
    const int quad = lane >> 4;
    const int bid  = blockIdx.x;
    const int b    = bid >> 4;            // batch image
    const int hw0  = (bid & 15) << 6;     // block's 64-row hw origin

    const float* zb = z + (size_t)b * (NC * NHW);
    const unsigned short* ap0 = cb + (size_t)(wv * 16) * 4096 + lane * 8;

    // ---- issue first cb tile NOW: phase-A z latency covers its L2 trip ----
    bf16x8 pa[8], pb[8];
#pragma unroll
    for (int cc = 0; cc < 8; ++cc) pa[cc] = *(const bf16x8*)(ap0 + cc * 512);

    // ---- Phase A: wave packs ITS 16 z vectors (nt = wv) into LDS ----------
    {
        const int hwc = hw0 + wv * 16 + n;     // this wave's N-tile column
#pragma unroll
        for (int cc = 0; cc < 8; ++cc) {
            const float* zp = zb + (size_t)(cc * 32 + quad * 8) * NHW + hwc;
            union { unsigned short u[8]; bf16x8 v; } pk;
#pragma unroll
            for (int j = 0; j < 8; ++j) pk.u[j] = f2bf(zp[(size_t)j * NHW]);
            *(bf16x8*)&zfrag[wv][cc][lane * 8] = pk.v;   // 1 KB contiguous/wave
        }
    }
    __syncthreads();

    // ---- all waves read all 4 N-tiles (32 x ds_read_b128, 0-conflict) -----
    bf16x8 bfr[4][8];
#pragma unroll
    for (int nt = 0; nt < 4; ++nt)
#pragma unroll
        for (int cc = 0; cc < 8; ++cc)
            bfr[nt][cc] = *(const bf16x8*)&zfrag[nt][cc][lane * 8];

    // ---- Main loop: ping-pong prefetch of cb tiles (r9, verified) ---------
    float bv[4] = {FLT_MAX, FLT_MAX, FLT_MAX, FLT_MAX};
    int   bi[4] = {0, 0, 0, 0};

#define MT_BODY(MT, CUR, NXT, PREF)                                            \
    {                                                                          \
        if (PREF) {                                                            \
            const unsigned short* apn = ap0 + (size_t)((MT) + 1) * 4096;       \
            _Pragma("unroll")                                                  \
            for (int cc = 0; cc < 8; ++cc)                                     \
                NXT[cc] = *(const bf16x8*)(apn + cc * 512);                    \
        }                                                                      \
        const int kt = wv * 256 + (MT) * 16;                                   \
        const f32x4 w4 = *(const f32x4*)(wsq + kt + quad * 4);                 \
        f32x4 acc[4];                                                          \
        _Pragma("unroll")                                                      \
        for (int nt = 0; nt < 4; ++nt) acc[nt] = w4;                           \
        _Pragma("unroll")                                                      \
        for (int cc = 0; cc < 8; ++cc) {                                       \
            acc[0] = __builtin_amdgcn_mfma_f32_16x16x32_bf16(CUR[cc], bfr[0][cc], acc[0], 0, 0, 0); \
            acc[1] = __builtin_amdgcn_mfma_f32_16x16x32_bf16(CUR[cc], bfr[1][cc], acc[1], 0, 0, 0); \
            acc[2] = __builtin_amdgcn_mfma_f32_16x16x32_bf16(CUR[cc], bfr[2][cc], acc[2], 0, 0, 0); \
            acc[3] = __builtin_amdgcn_mfma_f32_16x16x32_bf16(CUR[cc], bfr[3][cc], acc[3], 0, 0, 0); \
        }                                                                      \
        _Pragma("unroll")                                                      \
        for (int nt = 0; nt < 4; ++nt) {                                       \
            _Pragma("unroll")                                                  \
            for (int r = 0; r < 4; ++r) {                                      \
                const float v = acc[nt][r];                                    \
                if (v < bv[nt]) { bv[nt] = v; bi[nt] = kt + quad * 4 + r; }    \
            }                                                                  \
        }                                                                      \
    }

    for (int mt2 = 0; mt2 < 8; ++mt2) {
        const int mt = mt2 * 2;
        MT_BODY(mt,     pa, pb, true);
        MT_BODY(mt + 1, pb, pa, (mt2 < 7));
    }
#undef MT_BODY

    // ---- cross-quad argmin (lanes n, n+16, n+32, n+48) --------------------
#pragma unroll
    for (int nt = 0; nt < 4; ++nt) {
#pragma unroll
        for (int off = 16; off <= 32; off <<= 1) {
            const float ov = __shfl_xor(bv[nt], off, 64);
            const int   ok = __shfl_xor(bi[nt], off, 64);
            if (ov < bv[nt] || (ov == bv[nt] && ok < bi[nt])) { bv[nt] = ov; bi[nt] = ok; }
        }
    }
    if (lane < 16) {
#pragma unroll
        for (int nt = 0; nt < 4; ++nt) {
            sval[wv][nt * 16 + lane] = bv[nt];
            sidx[wv][nt * 16 + lane] = bi[nt];
        }
    }
    __syncthreads();

    // ---- cross-wave argmin over the 4 code quarters -----------------------
    if (tid < 64) {
        float bestv = sval[0][tid];
        int   besti = sidx[0][tid];
#pragma unroll
        for (int q = 1; q < 4; ++q) {
            const float v = sval[q][tid];
            const int   k = sidx[q][tid];
            if (v < bestv || (v == bestv && k < besti)) { bestv = v; besti = k; }
        }
        fidx[tid] = besti;
        atomicAdd(&counts[besti], 1u);
    }
    __syncthreads();

    // ---- Phase 2: gather codebook rows, write quantized, accumulate loss --
    float lsum = 0.f;
    const int hwl = tid & 63;
    const int cg  = tid >> 6;             // 0..3 -> c range [cg*64, cg*64+64)
    const int myk = fidx[hwl];
    const float* wr  = w + myk * NC;
    const float* zp2 = zb + hw0 + hwl;
    float*       op  = out + (size_t)b * (NC * NHW) + hw0 + hwl;
#pragma unroll 4
    for (int p = 0; p < 16; ++p) {
        const int c0 = cg * 64 + p * 4;
        const float4 q4 = *(const float4*)(wr + c0);
        const float qa[4] = {q4.x, q4.y, q4.z, q4.w};
#pragma unroll
        for (int u = 0; u < 4; ++u) {
            const int c = c0 + u;
            const float zv = zp2[(size_t)c * NHW];
            const float d = qa[u] - zv;
            lsum = fmaf(d, d, lsum);
            op[(size_t)c * NHW] = qa[u];
        }
    }
#pragma unroll
    for (int off = 32; off; off >>= 1) lsum += __shfl_down(lsum, off, 64);
    if (lane == 0) lred[wv] = lsum;
    __syncthreads();
    if (tid == 0)
        atomicAdd(loss_sum, lred[0] + lred[1] + lred[2] + lred[3]);
}

// ---------------- K3: finalize loss + perplexity ----------------
__global__ __launch_bounds__(256) void vq_final(const unsigned int* __restrict__ counts,
                                                const float* __restrict__ loss_sum,
                                                float* __restrict__ out) {
    __shared__ float red[4];
    const int tid = threadIdx.x;
    float s = 0.f;
#pragma unroll
    for (int p = 0; p < 4; ++p) {
        const float pr = (float)counts[tid + p * 256] * (1.f / 32768.f);
        s = fmaf(pr, logf(pr + 1e-10f), s);
    }
#pragma unroll
    for (int off = 32; off; off >>= 1) s += __shfl_down(s, off, 64);
    if ((tid & 63) == 0) red[tid >> 6] = s;
    __syncthreads();
    if (tid == 0) {
        const float tot = red[0] + red[1] + red[2] + red[3];
        out[NELEM]     = loss_sum[0] * (1.25f / (float)NELEM);
        out[NELEM + 1] = expf(-tot);
    }
}

extern "C" void kernel_launch(void* const* d_in, const int* in_sizes, int n_in,
                              void* d_out, int out_size, void* d_ws, size_t ws_size,
                              hipStream_t stream) {
    const float* z = (const float*)d_in[0];
    const float* w = (const float*)d_in[1];
    float* out = (float*)d_out;

    float*          wsq      = (float*)d_ws;
    unsigned int*   counts   = (unsigned int*)((char*)d_ws + 4096);
    float*          loss_sum = (float*)((char*)d_ws + 8192);
    unsigned short* cbfrag   = (unsigned short*)((char*)d_ws + 16384);  // 512 KB

    vq_prep  <<<64,  256, 0, stream>>>(w, cbfrag, wsq, counts, loss_sum);
    vq_main11<<<512, 256, 0, stream>>>(z, w, wsq, cbfrag, counts, loss_sum, out);
    vq_final <<<1,   256, 0, stream>>>(counts, loss_sum, out);
}

// Round 12
// 114.836 us; speedup vs baseline: 1.5078x; 1.0066x over previous
//
#include <hip/hip_runtime.h>
#include <float.h>
#include <math.h>
#include <stdint.h>

// VQ-VAE VectorQuantizer — round 14: r13 + coalesced phase-2 via LDS quant
// tile (gather stays thread-per-hw; z-read/loss/store remapped to float4).
//
// z_e: (32, 256, 32, 32) fp32, weight: (1024, 256) fp32
// outputs concat: quantized_st (8388608) + loss (1) + perplexity (1)
//
// History: r9/r13 verified best (main 44, total 115.3-115.6). Register
// audit: bfr(128)+pa/pb(64) AGPRs + 116 VGPRs ~ 244/256 unified -> no
// depth-2 headroom (r10 spill explained); depth x width trades are
// cover-neutral. Last un-attacked term: phase 2 issues 128 scalar 4KB-
// strided z-reads/stores per thread (64 lines per wave-instr). r7's split
// scatter proved the float4-along-hw mapping is ~free; r6 regressed only
// because it also broke the w-gather. r14: keep w-gather as-is (thread-per-
// hw float4 over c) but write into LDS qt[256][66] fp32 (r4-proven 2-way
// layout, overlays dead zfrag), barrier, then lanes own 4 consecutive hw:
// z re-read + out store become fully-coalesced float4 (16 instrs/thread).
// Loss reassociation only (already nondeterministic via float atomics).
// Argmin/quantized bytes untouched.
//
// score[k][n] = wsq[k] - 2*w_k.z_n  via  mfma_f32_16x16x32_bf16:
//   A (M=16 codes)  = -2*w  (bf16, A-frag order, streamed from L2,
//                            1-deep register ping-pong)
//   B (N=16 z vecs) =  z    (bf16, packed once per block via LDS)
//   C init          =  wsq[k]
//
// ws layout (bytes): [0,4096) wsq f32 | [4096,8192) counts u32
//                    [8192,8196) loss_sum f32 | [16384, 16384+524288) cbfrag

#define NB   32
#define NC   256
#define NHW  1024
#define NK   1024
#define NELEM (NB*NC*NHW)   // 8388608

typedef __attribute__((ext_vector_type(8))) short bf16x8;   // 8 bf16 = 4 VGPRs
typedef __attribute__((ext_vector_type(4))) float f32x4;

__device__ __forceinline__ unsigned short f2bf(float f) {   // RTN fp32->bf16
    unsigned u = __float_as_uint(f);
    u += 0x7FFFu + ((u >> 16) & 1u);
    return (unsigned short)(u >> 16);
}

// ---------------- K1: prep — pack A-frags (-2w bf16) + wsq + zero accums ---
__global__ __launch_bounds__(256) void vq_prep(const float* __restrict__ w,
                                               unsigned short* __restrict__ cb,
                                               float* __restrict__ wsq,
                                               unsigned int* __restrict__ counts,
                                               float* __restrict__ loss_sum) {
    __shared__ float swsq[4][16];
    const int t   = blockIdx.x;          // code tile 0..63 (16 codes each)
    const int tid = threadIdx.x;
    float sq = 0.f;
#pragma unroll
    for (int rep = 0; rep < 2; ++rep) {
        const int p = tid + rep * 256;   // 0..511
        const int cc = p >> 6, l = p & 63;
        const int n = l & 15, quad = l >> 4;
        const float* src = w + (t * 16 + n) * NC + cc * 32 + quad * 8;
        const float4 f0 = *(const float4*)src;
        const float4 f1 = *(const float4*)(src + 4);
        union { unsigned short u[8]; uint4 v; } pk;
        pk.u[0] = f2bf(-2.f * f0.x); pk.u[1] = f2bf(-2.f * f0.y);
        pk.u[2] = f2bf(-2.f * f0.z); pk.u[3] = f2bf(-2.f * f0.w);
        pk.u[4] = f2bf(-2.f * f1.x); pk.u[5] = f2bf(-2.f * f1.y);
        pk.u[6] = f2bf(-2.f * f1.z); pk.u[7] = f2bf(-2.f * f1.w);
        *(uint4*)(cb + (size_t)t * 4096 + cc * 512 + l * 8) = pk.v;
        sq = fmaf(f0.x, f0.x, sq); sq = fmaf(f0.y, f0.y, sq);
        sq = fmaf(f0.z, f0.z, sq); sq = fmaf(f0.w, f0.w, sq);
        sq = fmaf(f1.x, f1.x, sq); sq = fmaf(f1.y, f1.y, sq);
        sq = fmaf(f1.z, f1.z, sq); sq = fmaf(f1.w, f1.w, sq);
    }
    sq += __shfl_xor(sq, 16, 64);
    sq += __shfl_xor(sq, 32, 64);
    const int wv = tid >> 6, lane = tid & 63;
    if (lane < 16) swsq[wv][lane] = sq;
    __syncthreads();
    if (tid < 16)
        wsq[t * 16 + tid] = swsq[0][tid] + swsq[1][tid] + swsq[2][tid] + swsq[3][tid];
    if (t == 0) {
        for (int i = tid; i < NK; i += 256) counts[i] = 0u;
        if (tid == 0) loss_sum[0] = 0.f;
    }
}

// ---------------- K2: main — shared z-frags + ping-pong argmin + LDS-routed
//                  coalesced phase 2.
// grid 512 x 256 (4 waves). Block: 64 z vecs (b = bid>>4, hw0 = (bid&15)*64).
// Wave wv owns code quarter [wv*256, wv*256+256) AND packs z N-tile nt=wv.
__global__ __launch_bounds__(256, 2) void vq_main12(const float* __restrict__ z,
                                                    const float* __restrict__ w,
                                                    const float* __restrict__ wsq,
                                                    const unsigned short* __restrict__ cb,
                                                    unsigned int* __restrict__ counts,
                                                    float* __restrict__ loss_sum,
                                                    float* __restrict__ out) {
    // smem overlays: zfrag (32 KB, phase A) then qt[256][66] fp32 (67.6 KB,
    // phase 2). Lifetimes separated by the argmin __syncthreads pair.
    __shared__ __align__(16) char smem[256 * 66 * 4];
    __shared__ float sval[4][64];
    __shared__ int   sidx[4][64];
    __shared__ int   fidx[64];
    __shared__ float lred[4];

    unsigned short (*zfrag)[8][512] = (unsigned short(*)[8][512])smem;
    float          (*qt)[66]        = (float(*)[66])smem;

    const int tid  = threadIdx.x;
    const int wv   = tid >> 6;            // code quarter 0..3 (= packed N-tile)
    const int lane = tid & 63;
    const int n    = lane & 15;
    const int quad = lane >> 4;
    const int bid  = blockIdx.x;
    const int b    = bid >> 4;            // batch image
    const int hw0  = (bid & 15) << 6;     // block's 64-row hw origin

    const float* zb = z + (size_t)b * (NC * NHW);
    const unsigned short* ap0 = cb + (size_t)(wv * 16) * 4096 + lane * 8;

    // ---- issue first cb tile NOW: phase-A z latency covers its L2 trip ----
    bf16x8 pa[8], pb[8];
#pragma unroll
    for (int cc = 0; cc < 8; ++cc) pa[cc] = *(const bf16x8*)(ap0 + cc * 512);

    // ---- Phase A: wave packs ITS 16 z vectors (nt = wv) into LDS ----------
    {
        const int hwc = hw0 + wv * 16 + n;     // this wave's N-tile column
#pragma unroll
        for (int cc = 0; cc < 8; ++cc) {
            const float* zp = zb + (size_t)(cc * 32 + quad * 8) * NHW + hwc;
            union { unsigned short u[8]; bf16x8 v; } pk;
#pragma unroll
            for (int j = 0; j < 8; ++j) pk.u[j] = f2bf(zp[(size_t)j * NHW]);
            *(bf16x8*)&zfrag[wv][cc][lane * 8] = pk.v;   // 1 KB contiguous/wave
        }
    }
    __syncthreads();

    // ---- all waves read all 4 N-tiles (32 x ds_read_b128, 0-conflict) -----
    bf16x8 bfr[4][8];
#pragma unroll
    for (int nt = 0; nt < 4; ++nt)
#pragma unroll
        for (int cc = 0; cc < 8; ++cc)
            bfr[nt][cc] = *(const bf16x8*)&zfrag[nt][cc][lane * 8];

    // ---- Main loop: ping-pong prefetch of cb tiles (r9, verified) ---------
    float bv[4] = {FLT_MAX, FLT_MAX, FLT_MAX, FLT_MAX};
    int   bi[4] = {0, 0, 0, 0};

#define MT_BODY(MT, CUR, NXT, PREF)                                            \
    {                                                                          \
        if (PREF) {                                                            \
            const unsigned short* apn = ap0 + (size_t)((MT) + 1) * 4096;       \
            _Pragma("unroll")                                                  \
            for (int cc = 0; cc < 8; ++cc)                                     \
                NXT[cc] = *(const bf16x8*)(apn + cc * 512);                    \
        }                                                                      \
        const int kt = wv * 256 + (MT) * 16;                                   \
        const f32x4 w4 = *(const f32x4*)(wsq + kt + quad * 4);                 \
        f32x4 acc[4];                                                          \
        _Pragma("unroll")                                                      \
        for (int nt = 0; nt < 4; ++nt) acc[nt] = w4;                           \
        _Pragma("unroll")                                                      \
        for (int cc = 0; cc < 8; ++cc) {                                       \
            acc[0] = __builtin_amdgcn_mfma_f32_16x16x32_bf16(CUR[cc], bfr[0][cc], acc[0], 0, 0, 0); \
            acc[1] = __builtin_amdgcn_mfma_f32_16x16x32_bf16(CUR[cc], bfr[1][cc], acc[1], 0, 0, 0); \
            acc[2] = __builtin_amdgcn_mfma_f32_16x16x32_bf16(CUR[cc], bfr[2][cc], acc[2], 0, 0, 0); \
            acc[3] = __builtin_amdgcn_mfma_f32_16x16x32_bf16(CUR[cc], bfr[3][cc], acc[3], 0, 0, 0); \
        }                                                                      \
        _Pragma("unroll")                                                      \
        for (int nt = 0; nt < 4; ++nt) {                                       \
            _Pragma("unroll")                                                  \
            for (int r = 0; r < 4; ++r) {                                      \
                const float v = acc[nt][r];                                    \
                if (v < bv[nt]) { bv[nt] = v; bi[nt] = kt + quad * 4 + r; }    \
            }                                                                  \
        }                                                                      \
    }

    for (int mt2 = 0; mt2 < 8; ++mt2) {
        const int mt = mt2 * 2;
        MT_BODY(mt,     pa, pb, true);
        MT_BODY(mt + 1, pb, pa, (mt2 < 7));
    }
#undef MT_BODY

    // ---- cross-quad argmin (lanes n, n+16, n+32, n+48) --------------------
#pragma unroll
    for (int nt = 0; nt < 4; ++nt) {
#pragma unroll
        for (int off = 16; off <= 32; off <<= 1) {
            const float ov = __shfl_xor(bv[nt], off, 64);
            const int   ok = __shfl_xor(bi[nt], off, 64);
            if (ov < bv[nt] || (ov == bv[nt] && ok < bi[nt])) { bv[nt] = ov; bi[nt] = ok; }
        }
    }
    if (lane < 16) {
#pragma unroll
        for (int nt = 0; nt < 4; ++nt) {
            sval[wv][nt * 16 + lane] = bv[nt];
            sidx[wv][nt * 16 + lane] = bi[nt];
        }
    }
    __syncthreads();              // also: all waves done reading zfrag

    // ---- cross-wave argmin over the 4 code quarters -----------------------
    if (tid < 64) {
        float bestv = sval[0][tid];
        int   besti = sidx[0][tid];
#pragma unroll
        for (int q = 1; q < 4; ++q) {
            const float v = sval[q][tid];
            const int   k = sidx[q][tid];
            if (v < bestv || (v == bestv && k < besti)) { bestv = v; besti = k; }
        }
        fidx[tid] = besti;
        atomicAdd(&counts[besti], 1u);
    }
    __syncthreads();              // fidx ready; zfrag dead -> qt may reuse smem

    // ---- Phase 2a: gather codebook rows (proven pattern) -> LDS quant tile
    {
        const int hwl = tid & 63;
        const int cg  = tid >> 6;         // 0..3 -> c range [cg*64, cg*64+64)
        const int myk = fidx[hwl];
        const float* wr = w + myk * NC;
#pragma unroll
        for (int p = 0; p < 16; ++p) {
            const int c0 = cg * 64 + p * 4;
            const float4 q4 = *(const float4*)(wr + c0);
            qt[c0 + 0][hwl] = q4.x;       // banks (2c+hwl)%32: 2-way
            qt[c0 + 1][hwl] = q4.y;
            qt[c0 + 2][hwl] = q4.z;
            qt[c0 + 3][hwl] = q4.w;
        }
    }
    __syncthreads();

    // ---- Phase 2b: coalesced z re-read + loss + float4 out stores ---------
    float lsum = 0.f;
    {
        const int hw4 = (tid & 15) * 4;   // 4 consecutive hw per thread
        const int cq  = tid >> 4;         // 0..15; c = cq + 16p
        const float* zp2 = zb + hw0 + hw4;
        float*       op  = out + (size_t)b * (NC * NHW) + hw0 + hw4;
#pragma unroll
        for (int p = 0; p < 16; ++p) {
            const int c = cq + p * 16;
            const float4 zq = *(const float4*)(zp2 + (size_t)c * NHW);
            float4 q;
            q.x = qt[c][hw4 + 0];
            q.y = qt[c][hw4 + 1];
            q.z = qt[c][hw4 + 2];
            q.w = qt[c][hw4 + 3];
            float d;
            d = q.x - zq.x; lsum = fmaf(d, d, lsum);
            d = q.y - zq.y; lsum = fmaf(d, d, lsum);
            d = q.z - zq.z; lsum = fmaf(d, d, lsum);
            d = q.w - zq.w; lsum = fmaf(d, d, lsum);
            *(float4*)(op + (size_t)c * NHW) = q;     // 1 KB/wave-instr
        }
    }
#pragma unroll
    for (int off = 32; off; off >>= 1) lsum += __shfl_down(lsum, off, 64);
    if (lane == 0) lred[wv] = lsum;
    __syncthreads();
    if (tid == 0)
        atomicAdd(loss_sum, lred[0] + lred[1] + lred[2] + lred[3]);
}

// ---------------- K3: finalize loss + perplexity ----------------
__global__ __launch_bounds__(256) void vq_final(const unsigned int* __restrict__ counts,
                                                const float* __restrict__ loss_sum,
                                                float* __restrict__ out) {
    __shared__ float red[4];
    const int tid = threadIdx.x;
    float s = 0.f;
#pragma unroll
    for (int p = 0; p < 4; ++p) {
        const float pr = (float)counts[tid + p * 256] * (1.f / 32768.f);
        s = fmaf(pr, logf(pr + 1e-10f), s);
    }
#pragma unroll
    for (int off = 32; off; off >>= 1) s += __shfl_down(s, off, 64);
    if ((tid & 63) == 0) red[tid >> 6] = s;
    __syncthreads();
    if (tid == 0) {
        const float tot = red[0] + red[1] + red[2] + red[3];
        out[NELEM]     = loss_sum[0] * (1.25f / (float)NELEM);
        out[NELEM + 1] = expf(-tot);
    }
}

extern "C" void kernel_launch(void* const* d_in, const int* in_sizes, int n_in,
                              void* d_out, int out_size, void* d_ws, size_t ws_size,
                              hipStream_t stream) {
    const float* z = (const float*)d_in[0];
    const float* w = (const float*)d_in[1];
    float* out = (float*)d_out;

    float*          wsq      = (float*)d_ws;
    unsigned int*   counts   = (unsigned int*)((char*)d_ws + 4096);
    float*          loss_sum = (float*)((char*)d_ws + 8192);
    unsigned short* cbfrag   = (unsigned short*)((char*)d_ws + 16384);  // 512 KB

    vq_prep  <<<64,  256, 0, stream>>>(w, cbfrag, wsq, counts, loss_sum);
    vq_main12<<<512, 256, 0, stream>>>(z, w, wsq, cbfrag, counts, loss_sum, out);
    vq_final <<<1,   256, 0, stream>>>(counts, loss_sum, out);
}

// Round 13
// 112.605 us; speedup vs baseline: 1.5377x; 1.0198x over previous
//
#include <hip/hip_runtime.h>
#include <float.h>
#include <math.h>
#include <stdint.h>

// VQ-VAE VectorQuantizer — round 15: r14 + wsq register prefetch (breaks the
// per-iteration vmcnt(0) drain in the mt loop).
//
// z_e: (32, 256, 32, 32) fp32, weight: (1024, 256) fp32
// outputs concat: quantized_st (8388608) + loss (1) + perplexity (1)
//
// History: r9 ping-pong = main 51.7->44; r14 coalesced phase 2 = total 114.8
// (best). Waitcnt analysis: MT_BODY loads w4 (wsq) AFTER the 8 NXT cb
// prefetches and consumes it immediately for acc init -> compiler must emit
// an effectively-vmcnt(0) wait, draining the prefetches it was supposed to
// keep in flight. r15: w4 is software-prefetched one tile ahead into a
// register (w4cur/w4n swap). acc-init now waits on a load issued a full
// MFMA block earlier -> counted wait leaves 8 cb loads + 1 wsq load in
// flight across each MFMA block. Same values, same order, same tie-breaks
// -> bit-identical outputs. Depth-2 remains blocked (r10 spill, r11 race).
//
// score[k][n] = wsq[k] - 2*w_k.z_n  via  mfma_f32_16x16x32_bf16:
//   A (M=16 codes)  = -2*w  (bf16, A-frag order, streamed from L2,
//                            1-deep register ping-pong)
//   B (N=16 z vecs) =  z    (bf16, packed once per block via LDS)
//   C init          =  wsq[k]  (register-prefetched 1 tile ahead)
//
// ws layout (bytes): [0,4096) wsq f32 | [4096,8192) counts u32
//                    [8192,8196) loss_sum f32 | [16384, 16384+524288) cbfrag

#define NB   32
#define NC   256
#define NHW  1024
#define NK   1024
#define NELEM (NB*NC*NHW)   // 8388608

typedef __attribute__((ext_vector_type(8))) short bf16x8;   // 8 bf16 = 4 VGPRs
typedef __attribute__((ext_vector_type(4))) float f32x4;

__device__ __forceinline__ unsigned short f2bf(float f) {   // RTN fp32->bf16
    unsigned u = __float_as_uint(f);
    u += 0x7FFFu + ((u >> 16) & 1u);
    return (unsigned short)(u >> 16);
}

// ---------------- K1: prep — pack A-frags (-2w bf16) + wsq + zero accums ---
__global__ __launch_bounds__(256) void vq_prep(const float* __restrict__ w,
                                               unsigned short* __restrict__ cb,
                                               float* __restrict__ wsq,
                                               unsigned int* __restrict__ counts,
                                               float* __restrict__ loss_sum) {
    __shared__ float swsq[4][16];
    const int t   = blockIdx.x;          // code tile 0..63 (16 codes each)
    const int tid = threadIdx.x;
    float sq = 0.f;
#pragma unroll
    for (int rep = 0; rep < 2; ++rep) {
        const int p = tid + rep * 256;   // 0..511
        const int cc = p >> 6, l = p & 63;
        const int n = l & 15, quad = l >> 4;
        const float* src = w + (t * 16 + n) * NC + cc * 32 + quad * 8;
        const float4 f0 = *(const float4*)src;
        const float4 f1 = *(const float4*)(src + 4);
        union { unsigned short u[8]; uint4 v; } pk;
        pk.u[0] = f2bf(-2.f * f0.x); pk.u[1] = f2bf(-2.f * f0.y);
        pk.u[2] = f2bf(-2.f * f0.z); pk.u[3] = f2bf(-2.f * f0.w);
        pk.u[4] = f2bf(-2.f * f1.x); pk.u[5] = f2bf(-2.f * f1.y);
        pk.u[6] = f2bf(-2.f * f1.z); pk.u[7] = f2bf(-2.f * f1.w);
        *(uint4*)(cb + (size_t)t * 4096 + cc * 512 + l * 8) = pk.v;
        sq = fmaf(f0.x, f0.x, sq); sq = fmaf(f0.y, f0.y, sq);
        sq = fmaf(f0.z, f0.z, sq); sq = fmaf(f0.w, f0.w, sq);
        sq = fmaf(f1.x, f1.x, sq); sq = fmaf(f1.y, f1.y, sq);
        sq = fmaf(f1.z, f1.z, sq); sq = fmaf(f1.w, f1.w, sq);
    }
    sq += __shfl_xor(sq, 16, 64);
    sq += __shfl_xor(sq, 32, 64);
    const int wv = tid >> 6, lane = tid & 63;
    if (lane < 16) swsq[wv][lane] = sq;
    __syncthreads();
    if (tid < 16)
        wsq[t * 16 + tid] = swsq[0][tid] + swsq[1][tid] + swsq[2][tid] + swsq[3][tid];
    if (t == 0) {
        for (int i = tid; i < NK; i += 256) counts[i] = 0u;
        if (tid == 0) loss_sum[0] = 0.f;
    }
}

// ---------------- K2: main — shared z-frags + dual-prefetch argmin + LDS-
//                  routed coalesced phase 2.
// grid 512 x 256 (4 waves). Block: 64 z vecs (b = bid>>4, hw0 = (bid&15)*64).
// Wave wv owns code quarter [wv*256, wv*256+256) AND packs z N-tile nt=wv.
__global__ __launch_bounds__(256, 2) void vq_main13(const float* __restrict__ z,
                                                    const float* __restrict__ w,
                                                    const float* __restrict__ wsq,
                                                    const unsigned short* __restrict__ cb,
                                                    unsigned int* __restrict__ counts,
                                                    float* __restrict__ loss_sum,
                                                    float* __restrict__ out) {
    // smem overlays: zfrag (32 KB, phase A) then qt[256][66] fp32 (67.6 KB,
    // phase 2). Lifetimes separated by the argmin __syncthreads pair.
    __shared__ __align__(16) char smem[256 * 66 * 4];
    __shared__ float sval[4][64];
    __shared__ int   sidx[4][64];
    __shared__ int   fidx[64];
    __shared__ float lred[4];

    unsigned short (*zfrag)[8][512] = (unsigned short(*)[8][512])smem;
    float          (*qt)[66]        = (float(*)[66])smem;

    const int tid  = threadIdx.x;
    const int wv   = tid >> 6;            // code quarter 0..3 (= packed N-tile)
    const int lane = tid & 63;
    const int n    = lane & 15;
    const int quad = lane >> 4;
    const int bid  = blockIdx.x;
    const int b    = bid >> 4;            // batch image
    const int hw0  = (bid & 15) << 6;     // block's 64-row hw origin

    const float* zb = z + (size_t)b * (NC * NHW);
    const unsigned short* ap0 = cb + (size_t)(wv * 16) * 4096 + lane * 8;

    // ---- issue first cb tile + first wsq NOW: phase-A latency covers them -
    bf16x8 pa[8], pb[8];
#pragma unroll
    for (int cc = 0; cc < 8; ++cc) pa[cc] = *(const bf16x8*)(ap0 + cc * 512);
    f32x4 w4cur = *(const f32x4*)(wsq + wv * 256 + quad * 4);

    // ---- Phase A: wave packs ITS 16 z vectors (nt = wv) into LDS ----------
    {
        const int hwc = hw0 + wv * 16 + n;     // this wave's N-tile column
#pragma unroll
        for (int cc = 0; cc < 8; ++cc) {
            const float* zp = zb + (size_t)(cc * 32 + quad * 8) * NHW + hwc;
            union { unsigned short u[8]; bf16x8 v; } pk;
#pragma unroll
            for (int j = 0; j < 8; ++j) pk.u[j] = f2bf(zp[(size_t)j * NHW]);
            *(bf16x8*)&zfrag[wv][cc][lane * 8] = pk.v;   // 1 KB contiguous/wave
        }
    }
    __syncthreads();

    // ---- all waves read all 4 N-tiles (32 x ds_read_b128, 0-conflict) -----
    bf16x8 bfr[4][8];
#pragma unroll
    for (int nt = 0; nt < 4; ++nt)
#pragma unroll
        for (int cc = 0; cc < 8; ++cc)
            bfr[nt][cc] = *(const bf16x8*)&zfrag[nt][cc][lane * 8];

    // ---- Main loop: ping-pong cb prefetch + 1-ahead wsq register prefetch -
    float bv[4] = {FLT_MAX, FLT_MAX, FLT_MAX, FLT_MAX};
    int   bi[4] = {0, 0, 0, 0};

#define MT_BODY(MT, CUR, NXT, PREF)                                            \
    {                                                                          \
        if (PREF) {                                                            \
            const unsigned short* apn = ap0 + (size_t)((MT) + 1) * 4096;       \
            _Pragma("unroll")                                                  \
            for (int cc = 0; cc < 8; ++cc)                                     \
                NXT[cc] = *(const bf16x8*)(apn + cc * 512);                    \
        }                                                                      \
        /* wsq for NEXT tile: consumed next body, so its wait is counted   */  \
        /* (not vmcnt(0)) and this body's acc-init needs no fresh drain.   */  \
        const f32x4 w4n = *(const f32x4*)(wsq + wv * 256 +                     \
                                          (((MT) + 1) & 15) * 16 + quad * 4);  \
        const int kt = wv * 256 + (MT) * 16;                                   \
        f32x4 acc[4];                                                          \
        _Pragma("unroll")                                                      \
        for (int nt = 0; nt < 4; ++nt) acc[nt] = w4cur;                        \
        _Pragma("unroll")                                                      \
        for (int cc = 0; cc < 8; ++cc) {                                       \
            acc[0] = __builtin_amdgcn_mfma_f32_16x16x32_bf16(CUR[cc], bfr[0][cc], acc[0], 0, 0, 0); \
            acc[1] = __builtin_amdgcn_mfma_f32_16x16x32_bf16(CUR[cc], bfr[1][cc], acc[1], 0, 0, 0); \
            acc[2] = __builtin_amdgcn_mfma_f32_16x16x32_bf16(CUR[cc], bfr[2][cc], acc[2], 0, 0, 0); \
            acc[3] = __builtin_amdgcn_mfma_f32_16x16x32_bf16(CUR[cc], bfr[3][cc], acc[3], 0, 0, 0); \
        }                                                                      \
        _Pragma("unroll")                                                      \
        for (int nt = 0; nt < 4; ++nt) {                                       \
            _Pragma("unroll")                                                  \
            for (int r = 0; r < 4; ++r) {                                      \
                const float v = acc[nt][r];                                    \
                if (v < bv[nt]) { bv[nt] = v; bi[nt] = kt + quad * 4 + r; }    \
            }                                                                  \
        }                                                                      \
        w4cur = w4n;                                                           \
    }

    for (int mt2 = 0; mt2 < 8; ++mt2) {
        const int mt = mt2 * 2;
        MT_BODY(mt,     pa, pb, true);
        MT_BODY(mt + 1, pb, pa, (mt2 < 7));
    }
#undef MT_BODY

    // ---- cross-quad argmin (lanes n, n+16, n+32, n+48) --------------------
#pragma unroll
    for (int nt = 0; nt < 4; ++nt) {
#pragma unroll
        for (int off = 16; off <= 32; off <<= 1) {
            const float ov = __shfl_xor(bv[nt], off, 64);
            const int   ok = __shfl_xor(bi[nt], off, 64);
            if (ov < bv[nt] || (ov == bv[nt] && ok < bi[nt])) { bv[nt] = ov; bi[nt] = ok; }
        }
    }
    if (lane < 16) {
#pragma unroll
        for (int nt = 0; nt < 4; ++nt) {
            sval[wv][nt * 16 + lane] = bv[nt];
            sidx[wv][nt * 16 + lane] = bi[nt];
        }
    }
    __syncthreads();              // also: all waves done reading zfrag

    // ---- cross-wave argmin over the 4 code quarters -----------------------
    if (tid < 64) {
        float bestv = sval[0][tid];
        int   besti = sidx[0][tid];
#pragma unroll
        for (int q = 1; q < 4; ++q) {
            const float v = sval[q][tid];
            const int   k = sidx[q][tid];
            if (v < bestv || (v == bestv && k < besti)) { bestv = v; besti = k; }
        }
        fidx[tid] = besti;
        atomicAdd(&counts[besti], 1u);
    }
    __syncthreads();              // fidx ready; zfrag dead -> qt may reuse smem

    // ---- Phase 2a: gather codebook rows (proven pattern) -> LDS quant tile
    {
        const int hwl = tid & 63;
        const int cg  = tid >> 6;         // 0..3 -> c range [cg*64, cg*64+64)
        const int myk = fidx[hwl];
        const float* wr = w + myk * NC;
#pragma unroll
        for (int p = 0; p < 16; ++p) {
            const int c0 = cg * 64 + p * 4;
            const float4 q4 = *(const float4*)(wr + c0);
            qt[c0 + 0][hwl] = q4.x;       // banks (2c+hwl)%32: 2-way
            qt[c0 + 1][hwl] = q4.y;
            qt[c0 + 2][hwl] = q4.z;
            qt[c0 + 3][hwl] = q4.w;
        }
    }
    __syncthreads();

    // ---- Phase 2b: coalesced z re-read + loss + float4 out stores ---------
    float lsum = 0.f;
    {
        const int hw4 = (tid & 15) * 4;   // 4 consecutive hw per thread
        const int cq  = tid >> 4;         // 0..15; c = cq + 16p
        const float* zp2 = zb + hw0 + hw4;
        float*       op  = out + (size_t)b * (NC * NHW) + hw0 + hw4;
#pragma unroll
        for (int p = 0; p < 16; ++p) {
            const int c = cq + p * 16;
            const float4 zq = *(const float4*)(zp2 + (size_t)c * NHW);
            float4 q;
            q.x = qt[c][hw4 + 0];
            q.y = qt[c][hw4 + 1];
            q.z = qt[c][hw4 + 2];
            q.w = qt[c][hw4 + 3];
            float d;
            d = q.x - zq.x; lsum = fmaf(d, d, lsum);
            d = q.y - zq.y; lsum = fmaf(d, d, lsum);
            d = q.z - zq.z; lsum = fmaf(d, d, lsum);
            d = q.w - zq.w; lsum = fmaf(d, d, lsum);
            *(float4*)(op + (size_t)c * NHW) = q;     // 1 KB/wave-instr
        }
    }
#pragma unroll
    for (int off = 32; off; off >>= 1) lsum += __shfl_down(lsum, off, 64);
    if (lane == 0) lred[wv] = lsum;
    __syncthreads();
    if (tid == 0)
        atomicAdd(loss_sum, lred[0] + lred[1] + lred[2] + lred[3]);
}

// ---------------- K3: finalize loss + perplexity ----------------
__global__ __launch_bounds__(256) void vq_final(const unsigned int* __restrict__ counts,
                                                const float* __restrict__ loss_sum,
                                                float* __restrict__ out) {
    __shared__ float red[4];
    const int tid = threadIdx.x;
    float s = 0.f;
#pragma unroll
    for (int p = 0; p < 4; ++p) {
        const float pr = (float)counts[tid + p * 256] * (1.f / 32768.f);
        s = fmaf(pr, logf(pr + 1e-10f), s);
    }
#pragma unroll
    for (int off = 32; off; off >>= 1) s += __shfl_down(s, off, 64);
    if ((tid & 63) == 0) red[tid >> 6] = s;
    __syncthreads();
    if (tid == 0) {
        const float tot = red[0] + red[1] + red[2] + red[3];
        out[NELEM]     = loss_sum[0] * (1.25f / (float)NELEM);
        out[NELEM + 1] = expf(-tot);
    }
}

extern "C" void kernel_launch(void* const* d_in, const int* in_sizes, int n_in,
                              void* d_out, int out_size, void* d_ws, size_t ws_size,
                              hipStream_t stream) {
    const float* z = (const float*)d_in[0];
    const float* w = (const float*)d_in[1];
    float* out = (float*)d_out;

    float*          wsq      = (float*)d_ws;
    unsigned int*   counts   = (unsigned int*)((char*)d_ws + 4096);
    float*          loss_sum = (float*)((char*)d_ws + 8192);
    unsigned short* cbfrag   = (unsigned short*)((char*)d_ws + 16384);  // 512 KB

    vq_prep  <<<64,  256, 0, stream>>>(w, cbfrag, wsq, counts, loss_sum);
    vq_main13<<<512, 256, 0, stream>>>(z, w, wsq, cbfrag, counts, loss_sum, out);
    vq_final <<<1,   256, 0, stream>>>(counts, loss_sum, out);
}